// Round 5
// baseline (648.178 us; speedup 1.0000x reference)
//
#include <hip/hip_runtime.h>
#include <hip/hip_bf16.h>

// StackedLoRALinear on MI355X (gfx950). fp32 in/out, bf16 MFMA inside.
//
// Algebraic fold: out = x @ Weff^T + b, where
//   Weff = W + B' @ A_all,  B'[n,j=d*32+r] = lora_B[d,n,r],  A_all = lora_A flat [128,3072]
// Pipeline:
//   1. cvt x -> bf16 (8 elem/thread)
//   2. fused transpose-convert lora_B -> B' and lora_A -> A^T (bf16 [3072,128])
//   3. Weff = B' @ (A^T)^T + W  via 128^2 MFMA GEMM (KT=4, ADD_MAT, bf16 out)
//   4. out = xb @ Weff^T + b    via 256^2 MFMA GEMM, 2-barrier K-tile,
//      32x32x16 MFMA (v5)
//
// v5 = v4 structure with the MFMA shape switched 16x16x32 -> 32x32x16:
// same FLOPs, same 24 ds_read_b128/K-tile/wave, HALF the MFMA instructions,
// and the 32x32 pipe runs ~15% closer to peak (m119: 2495 vs 2176 TF).
// B-fragment reads split across the two halves to stay under the 256-reg
// occupancy budget (bf0 read in half1, bf1 in half2; B region is not
// overwritten until t+2 so the post-barrier read is safe).

typedef unsigned short ushort_t;
typedef short bf16x8 __attribute__((ext_vector_type(8)));   // 8 bf16 = 4 VGPRs
typedef float floatx4 __attribute__((ext_vector_type(4)));
typedef float floatx16 __attribute__((ext_vector_type(16)));
typedef unsigned short ushortx4 __attribute__((ext_vector_type(4)));
typedef unsigned short ushortx8 __attribute__((ext_vector_type(8)));

__device__ __forceinline__ ushort_t f2bf(float f) {
    __hip_bfloat16 h = __float2bfloat16(f);
    return *(ushort_t*)&h;
}

__device__ __forceinline__ void async_load16(const void* g, void* l) {
    __builtin_amdgcn_global_load_lds(
        (const __attribute__((address_space(1))) void*)g,
        (__attribute__((address_space(3))) void*)l,
        16, 0, 0);
}

#define MFMA16(a, b, c) __builtin_amdgcn_mfma_f32_16x16x32_bf16(a, b, c, 0, 0, 0)
#define MFMA32(a, b, c) __builtin_amdgcn_mfma_f32_32x32x16_bf16(a, b, c, 0, 0, 0)

// fp32 -> bf16, 8 elements/thread. n8 = n/8.
__global__ __launch_bounds__(256)
void cvt_kernel(const float* __restrict__ in, ushort_t* __restrict__ out, int n8) {
    int i = blockIdx.x * 256 + threadIdx.x;
    if (i < n8) {
        const float4 v0 = ((const float4*)in)[2 * i];
        const float4 v1 = ((const float4*)in)[2 * i + 1];
        ushortx8 o = { f2bf(v0.x), f2bf(v0.y), f2bf(v0.z), f2bf(v0.w),
                       f2bf(v1.x), f2bf(v1.y), f2bf(v1.z), f2bf(v1.w) };
        ((ushortx8*)out)[i] = o;
    }
}

// Fused LoRA factor transposes. Blocks [0,1536): B', blocks [1536,3072): A^T.
// B'[n*128 + d*32 + r] = bf16(lora_B[d*N*32 + n*32 + r]);  N=3072
// A^T[kk*128 + j]      = bf16(lora_A[j*3072 + kk]);  (lora_A flat = [128,3072])
__global__ __launch_bounds__(256)
void transpose_lora_kernel(const float* __restrict__ lb,
                           const float* __restrict__ la,
                           ushort_t* __restrict__ outB,
                           ushort_t* __restrict__ outA) {
    int bid = blockIdx.x;
    if (bid < 1536) {
        int idx = bid * 256 + threadIdx.x;      // 0 .. 393215
        int n = idx >> 7;
        int j = idx & 127;
        int d = j >> 5, r = j & 31;
        outB[idx] = f2bf(lb[(size_t)d * (3072 * 32) + (size_t)n * 32 + r]);
    } else {
        int idx = (bid - 1536) * 256 + threadIdx.x;
        int kk = idx >> 7;
        int j  = idx & 127;
        outA[idx] = f2bf(la[(size_t)j * 3072 + kk]);
    }
}

// ---------------------------------------------------------------------------
// 128^2 "B-transposed" GEMM (kept for the tiny Weff build, KT=4).
// ---------------------------------------------------------------------------
template <int KT, bool OUT_F32, bool ADD_MAT>
__global__ __launch_bounds__(256)
void gemm_bt_kernel(const ushort_t* __restrict__ A, int lda,
                    const ushort_t* __restrict__ B, int ldb,
                    const float* __restrict__ Cadd,   // [M,ldc] fp32 if ADD_MAT
                    const float* __restrict__ bias,   // [N] fp32 or null
                    void* __restrict__ Cv, int ldc)
{
    __shared__ ushort_t As[128 * 32];   // 8 KB
    __shared__ ushort_t Bs[128 * 32];   // 8 KB

    const int t    = threadIdx.x;
    const int lane = t & 63;
    const int wave = t >> 6;
    const int wr   = wave >> 1, wc = wave & 1;
    const int quad = lane >> 4, l16 = lane & 15;

    const int mBase = blockIdx.y * 128;
    const int nBase = blockIdx.x * 128;

    floatx4 acc[4][4] = {};

    const int p0 = t,       r0 = p0 >> 2, g0 = ((p0 & 3) ^ ((r0 >> 1) & 3)) << 3;
    const int p1 = t + 256, r1 = p1 >> 2, g1 = ((p1 & 3) ^ ((r1 >> 1) & 3)) << 3;
    const int qs = (quad ^ ((l16 >> 1) & 3)) << 3;

    for (int kt = 0; kt < KT; ++kt) {
        const int ko = kt * 32;

        async_load16(A + (size_t)(mBase + r0) * lda + ko + g0, &As[p0 * 8]);
        async_load16(A + (size_t)(mBase + r1) * lda + ko + g1, &As[p1 * 8]);
        async_load16(B + (size_t)(nBase + r0) * ldb + ko + g0, &Bs[p0 * 8]);
        async_load16(B + (size_t)(nBase + r1) * ldb + ko + g1, &Bs[p1 * 8]);

        __syncthreads();

        bf16x8 af[4], bf[4];
#pragma unroll
        for (int mi = 0; mi < 4; ++mi)
            af[mi] = *(const bf16x8*)&As[(wr * 64 + mi * 16 + l16) * 32 + qs];
#pragma unroll
        for (int ni = 0; ni < 4; ++ni)
            bf[ni] = *(const bf16x8*)&Bs[(wc * 64 + ni * 16 + l16) * 32 + qs];

#pragma unroll
        for (int mi = 0; mi < 4; ++mi)
#pragma unroll
            for (int ni = 0; ni < 4; ++ni)
                acc[mi][ni] = MFMA16(af[mi], bf[ni], acc[mi][ni]);

        __syncthreads();
    }

#pragma unroll
    for (int ni = 0; ni < 4; ++ni) {
        const int col = nBase + wc * 64 + ni * 16 + l16;
        const float bv = bias ? bias[col] : 0.0f;
#pragma unroll
        for (int mi = 0; mi < 4; ++mi) {
            const int row = mBase + wr * 64 + mi * 16 + quad * 4;
#pragma unroll
            for (int r = 0; r < 4; ++r) {
                float v = acc[mi][ni][r] + bv;
                if (ADD_MAT) v += Cadd[(size_t)(row + r) * ldc + col];
                if (OUT_F32) {
                    ((float*)Cv)[(size_t)(row + r) * ldc + col] = v;
                } else {
                    ((ushort_t*)Cv)[(size_t)(row + r) * ldc + col] = f2bf(v);
                }
            }
        }
    }
}

// ---------------------------------------------------------------------------
// Main GEMM: 256x256 tile, BK=64, 8 waves (2M x 4N), 2 barriers/K-tile,
// 32x32x16 MFMA. C[m,n] = sum_k A[m,k]*B[n,k] + bias[n].
//
// LDS (160 KiB): A regions {0, 32768} (parity t&1), B regions
// {65536, 98304, 131072} (t%3). Each region = 2 halves x 16 KiB (128 rows x
// 64 cols). Slot p (16 B) at row=p>>3, chunk s=p&7 holds global chunk
// s ^ (row&7) (XOR swizzle; write side linear for global_load_lds, source
// address pre-swizzled).
//
// Per-wave per K-tile: af[mi 0..3][ks 0..3] (16 ds_read_b128, rows mi*32+l32,
// chunk ks*2+hi), bf0/bf1[ks 0..3] (8 reads). MFMA: 4 mi x 2 nj x 4 ks = 32
// of 32x32x16.
//
// Sync proof (per K-tile t): early STAGE_B -> (t+2)%3 (last read at t-1,
// drained by its consuming MFMAs before t-1's barrier#2). STAGE_A -> parity
// t&1 after barrier#1 (af reads drained by lgkmcnt(0)). bf1 read after
// barrier#1 from B region t%3 (disjoint from both stage targets; its region
// is next written at t+1's STAGE_B, which is after t's barrier#2, and bf1
// reads are drained by their consuming MFMAs before barrier#2). vmcnt(8)
// before barrier#2 drains batch t-1 = tile t+1 resident.
// ---------------------------------------------------------------------------
__global__ __launch_bounds__(512)
void gemm256_kernel(const ushort_t* __restrict__ A,
                    const ushort_t* __restrict__ B,
                    const float* __restrict__ bias,
                    float* __restrict__ C)
{
    constexpr int LDA = 3072;   // = K = ldb = ldc
    constexpr int NT  = 48;     // K / 64
    constexpr int NBX = 12;     // N / 256

    __shared__ ushort_t smem_u[81920];          // 160 KiB
    char* const smem = (char*)smem_u;

    const int t    = threadIdx.x;
    const int lane = t & 63;
    const int wave = t >> 6;
    const int wr   = wave >> 2;        // 0..1 : M half (128 rows)
    const int wc   = wave & 3;         // 0..3 : N quarter (64 cols)
    const int l32  = lane & 31;
    const int hi   = lane >> 5;        // k-chunk selector for 32x32 operands

    // T1: bijective XCD swizzle (768 blocks, 768 % 8 == 0)
    const int bid = blockIdx.x;
    const int sw  = (bid & 7) * 96 + (bid >> 3);
    const int bx  = sw % NBX;
    const int by  = sw / NBX;
    const int mBase = by * 256;
    const int nBase = bx * 256;

    // ---- staging addresses (pre-swizzled global source, linear LDS dst) ----
    const int prow = t >> 3;                   // 0..63
    const int cg   = (t & 7) ^ (prow & 7);     // swizzled global chunk index
    const ushort_t* const aSrc = A + (size_t)(mBase + prow) * LDA + cg * 8;
    const ushort_t* const bSrc = B + (size_t)(nBase + prow) * LDA + cg * 8;

#define STAGE_A(off, h, ktv) do {                                           \
        const ushort_t* _s = aSrc + (size_t)(h) * 128 * LDA + (ktv) * 64;   \
        char* _d = smem + (off) + (h) * 16384 + t * 16;                     \
        async_load16(_s, _d);                                               \
        async_load16(_s + 64 * LDA, _d + 8192);                             \
    } while (0)
#define STAGE_B(off, h, ktv) do {                                           \
        const ushort_t* _s = bSrc + (size_t)(h) * 128 * LDA + (ktv) * 64;   \
        char* _d = smem + (off) + (h) * 16384 + t * 16;                     \
        async_load16(_s, _d);                                               \
        async_load16(_s + 64 * LDA, _d + 8192);                             \
    } while (0)

    // ---- LDS read geometry. Operand row = l32 (+32*mi / +32*nj), k-chunk =
    // ks*2 + hi. Stored chunk slot = chunk ^ (row&7); row&7 == l32&7 always
    // (row offsets are multiples of 32). Byte offset of chunk for ks:
    //   ((ks*2 ^ (hi ^ (l32&7))) << 4)   [ks*2 has bit0=0 so +hi == ^hi]
    const int q = hi ^ (l32 & 7);
    const int sx0 = ((0 ^ q)) << 4;
    const int sx1 = ((2 ^ q)) << 4;
    const int sx2 = ((4 ^ q)) << 4;
    const int sx3 = ((6 ^ q)) << 4;
    const int sxk[4] = { sx0, sx1, sx2, sx3 };

    const int aRdB = wr * 16384 + l32 * 128;                       // + mi*4096
    const int bRdB = (wc >> 1) * 16384 + ((wc & 1) * 64 + l32) * 128;  // + nj*4096

    floatx16 acc[4][2] = {};
    bf16x8 af[4][4];
    bf16x8 bf0[4], bf1[4];

    // ---- prologue: tile0 (A@0, B@65536) + tile1 (A@32768, B@98304) ----
    STAGE_A(0,      0, 0); STAGE_A(0,      1, 0);
    STAGE_B(65536,  0, 0); STAGE_B(65536,  1, 0);
    STAGE_A(32768,  0, 1); STAGE_A(32768,  1, 1);
    STAGE_B(98304,  0, 1); STAGE_B(98304,  1, 1);
    asm volatile("s_waitcnt vmcnt(8)" ::: "memory");   // tile0 resident
    __builtin_amdgcn_s_barrier();
    __builtin_amdgcn_sched_barrier(0);

    int aOff = 0;          // A region read this iter == A(t+2) stage target
    int bRdO = 65536;      // B region read this iter  (t%3)
    int bStO = 131072;     // B(t+2) stage target      ((t+2)%3)

    for (int kt = 0; kt < NT; ++kt) {
        const int ktN = (kt + 2 < NT) ? kt + 2 : NT - 1;   // clamp tail

        // ---- early stage: B(t+2) -> region free since tile t-1 ------------
        STAGE_B(bStO, 0, ktN);
        STAGE_B(bStO, 1, ktN);
        __builtin_amdgcn_sched_barrier(0);

        // ---- half 1: bf0 + all af reads, MFMA nj=0 ------------------------
#pragma unroll
        for (int ks = 0; ks < 4; ++ks)
            bf0[ks] = *(const bf16x8*)(smem + bRdO + bRdB + sxk[ks]);
#pragma unroll
        for (int mi = 0; mi < 4; ++mi)
#pragma unroll
            for (int ks = 0; ks < 4; ++ks)
                af[mi][ks] = *(const bf16x8*)(smem + aOff + aRdB + mi * 4096 + sxk[ks]);

#pragma unroll
        for (int ks = 0; ks < 4; ++ks)
#pragma unroll
            for (int mi = 0; mi < 4; ++mi)
                acc[mi][0] = MFMA32(af[mi][ks], bf0[ks], acc[mi][0]);

        asm volatile("s_waitcnt lgkmcnt(0)" ::: "memory");
        __builtin_amdgcn_sched_barrier(0);
        __builtin_amdgcn_s_barrier();      // #1: all waves' A-reads done

        // ---- stage A(t+2) into the parity region just released ------------
        STAGE_A(aOff, 0, ktN);
        STAGE_A(aOff, 1, ktN);
        __builtin_amdgcn_sched_barrier(0);

        // ---- half 2: bf1 reads + MFMA nj=1 (B region untouched by stages) -
        __builtin_amdgcn_s_setprio(1);
#pragma unroll
        for (int ks = 0; ks < 4; ++ks)
            bf1[ks] = *(const bf16x8*)(smem + bRdO + bRdB + 4096 + sxk[ks]);
#pragma unroll
        for (int ks = 0; ks < 4; ++ks)
#pragma unroll
            for (int mi = 0; mi < 4; ++mi)
                acc[mi][1] = MFMA32(af[mi][ks], bf1[ks], acc[mi][1]);
        __builtin_amdgcn_s_setprio(0);
        __builtin_amdgcn_sched_barrier(0);
        asm volatile("s_waitcnt vmcnt(8)" ::: "memory");   // tile t+1 resident
        __builtin_amdgcn_s_barrier();      // #2
        __builtin_amdgcn_sched_barrier(0);

        // rotate buffers
        aOff ^= 32768;
        bRdO = (bRdO == 131072) ? 65536 : bRdO + 32768;
        bStO = (bStO == 131072) ? 65536 : bStO + 32768;
    }

    // Drain tail junk DMAs before LDS is released to the next workgroup.
    asm volatile("s_waitcnt vmcnt(0)" ::: "memory");

    // Epilogue. 32x32 C/D layout (m74/m101): col = lane&31,
    // row = (reg&3) + 8*(reg>>2) + 4*(lane>>5).
#pragma unroll
    for (int nj = 0; nj < 2; ++nj) {
        const int col = nBase + wc * 64 + nj * 32 + l32;
        const float bv = bias[col];
#pragma unroll
        for (int mi = 0; mi < 4; ++mi) {
            const int row0 = mBase + wr * 128 + mi * 32 + 4 * hi;
#pragma unroll
            for (int reg = 0; reg < 16; ++reg) {
                const int row = row0 + (reg & 3) + 8 * (reg >> 2);
                C[(size_t)row * LDA + col] = acc[mi][nj][reg] + bv;
            }
        }
    }
#undef STAGE_A
#undef STAGE_B
}

extern "C" void kernel_launch(void* const* d_in, const int* in_sizes, int n_in,
                              void* d_out, int out_size, void* d_ws, size_t ws_size,
                              hipStream_t stream) {
    // Inputs (fp32): x[4,4096,3072], W[3072,3072], b[3072],
    //                lora_A[4,32,3072], lora_B[4,3072,32]
    const float* x  = (const float*)d_in[0];
    const float* W  = (const float*)d_in[1];
    const float* b  = (const float*)d_in[2];
    const float* lA = (const float*)d_in[3];
    const float* lB = (const float*)d_in[4];
    float* out = (float*)d_out;

    constexpr int M = 4 * 4096;        // 16384
    constexpr int N = 3072;
    constexpr int K = 3072;
    constexpr size_t nX  = (size_t)M * K;     // 50331648
    constexpr size_t nW  = (size_t)N * K;     //  9437184
    constexpr size_t nT  = (size_t)128 * K;   //   393216

    // Workspace (bf16 elems): xb | Weffb | Bp | At
    ushort_t* xb    = (ushort_t*)d_ws;
    ushort_t* Weffb = xb + nX;
    ushort_t* Bp    = Weffb + nW;
    ushort_t* At    = Bp + nT;

    // 1) x -> bf16 (8 elem/thread)
    cvt_kernel<<<nX / 8 / 256, 256, 0, stream>>>(x, xb, (int)(nX / 8));

    // 2) fused LoRA factor transposes (bf16 [3072,128], inner dim contiguous)
    transpose_lora_kernel<<<2 * (nT / 256), 256, 0, stream>>>(lB, lA, Bp, At);

    // 3) Weff[n,kk] = sum_j B'[n,j]*A^T[kk,j] + W[n,kk], bf16 out. K=128 -> KT=4.
    gemm_bt_kernel<4, false, true><<<dim3(N / 128, N / 128), 256, 0, stream>>>(
        Bp, 128, At, 128, W, nullptr, Weffb, N);

    // 4) out = xb @ Weff^T + b, fp32 out. 256^2 2-barrier, 32x32 MFMA.
    gemm256_kernel<<<(M / 256) * (N / 256), 512, 0, stream>>>(xb, Weffb, b, out);
}